// Round 10
// baseline (89.257 us; speedup 1.0000x reference)
//
#include <hip/hip_runtime.h>
#include <math.h>

#define FCT_REV 0.6079271018540267f   // 180/(pi*15) / (2*pi)  -> revolutions
#define DIVK 0.28782313662425575f     // ln(10000)/32
#define INV2PI 0.15915494309189535f

using bf16x8 = __attribute__((ext_vector_type(8))) short;
using f32x4  = __attribute__((ext_vector_type(4))) float;

__device__ inline short f2bf(float f) {
    union { float f; unsigned u; } v; v.f = f;
    unsigned r = v.u + 0x7FFFu + ((v.u >> 16) & 1u);
    return (short)(r >> 16);
}
__device__ inline float bf2f(short s) {
    union { unsigned u; float f; } v;
    v.u = ((unsigned)(unsigned short)s) << 16;
    return v.f;
}
__device__ inline float bflo(unsigned u) {
    union { unsigned q; float f; } v; v.q = u << 16; return v.f;
}
__device__ inline float bfhi(unsigned u) {
    union { unsigned q; float f; } v; v.q = u & 0xFFFF0000u; return v.f;
}
__device__ inline unsigned pk2(float lo, float hi) {
    return ((unsigned)(unsigned short)f2bf(hi) << 16) | (unsigned)(unsigned short)f2bf(lo);
}
__device__ inline float sinrev(float x) {  // sin(2*pi*x)
    float r; asm("v_sin_f32 %0, %1" : "=v"(r) : "v"(x)); return r;
}
__device__ inline float cosrev(float x) {  // cos(2*pi*x)
    float r; asm("v_cos_f32 %0, %1" : "=v"(r) : "v"(x)); return r;
}

// ---- prep: Wcat bf16 [704][512] + InT bf16 [b][n][k] + e2Wt[k][o] + zero stat/colsum ----
__global__ __launch_bounds__(256) void k_prep(
    const float* __restrict__ Wkp, const float* __restrict__ Wk,
    const float* __restrict__ Wv, const float* __restrict__ Wvp,
    const float* __restrict__ linW, const float* __restrict__ e1W,
    const float* __restrict__ e2W,
    const float* __restrict__ x, const float* __restrict__ pca,
    short* __restrict__ Wcatb, short* __restrict__ InTb,
    float* __restrict__ e2Wt, float* __restrict__ stat, float* __restrict__ colsum)
{
    __shared__ float ts[64][65];
    const int bid = blockIdx.x;
    const int t = threadIdx.x;
    if (bid < 176) {
        if (bid == 0) {
            for (int i = t; i < 2048; i += 256) colsum[i] = 0.f;
            for (int i = t; i < 512; i += 256) stat[i] = 0.f;
        } else if (bid == 1) {
            for (int i = t; i < 4096; i += 256) {
                int k = i >> 6, o = i & 63;
                e2Wt[k*64 + o] = e2W[o*64 + k];
            }
        }
        #pragma unroll
        for (int rr = 0; rr < 4; ++rr) {
            const int r = bid*4 + rr;
            for (int k = t; k < 512; k += 256) {
                float v = 0.f;
                if (r < 64) { if (k < 256) v = Wkp[r*256 + k]; }
                else if (r < 128) { int o = r-64;  v = (k<256) ? Wk[o*256+k]  : Wkp[o*256 + k-256]; }
                else if (r < 384) { int o = r-128; v = (k<256) ? Wv[o*256+k]  : Wvp[o*256 + k-256]; }
                else if (r < 640) { int o = r-384; if (k<256) v = linW[o*256+k]; }
                else {
                    int o = r-640;
                    if (k < 256) {
                        float a = 0.f;
                        for (int j = 0; j < 64; ++j) a = fmaf(e1W[j*64 + o], Wkp[j*256 + k], a);
                        v = a;
                    }
                }
                Wcatb[(size_t)r*512 + k] = f2bf(v);
            }
        }
    } else {
        const int id = bid - 176;             // 4b x 8kt x 8nt
        const int b  = id >> 6;
        const int kt = (id >> 3) & 7;
        const int nt = id & 7;
        const int k0 = kt*64, n0 = nt*64;
        const float* src = (k0 < 256) ? (x + ((size_t)b*256 + k0)*512)
                                      : (pca + ((size_t)b*256 + (k0-256))*512);
        #pragma unroll
        for (int i = 0; i < 16; ++i) {
            int idx = t + 256*i;
            int r = idx >> 6, c = idx & 63;
            ts[r][c] = src[(size_t)r*512 + n0 + c];
        }
        __syncthreads();
        short* dst = InTb + (size_t)b*512*512;
        #pragma unroll
        for (int i = 0; i < 16; ++i) {
            int idx = t + 256*i;
            int n = idx >> 6, k = idx & 63;
            dst[(size_t)(n0+n)*512 + k0 + k] = f2bf(ts[k][n]);
        }
    }
}

// ---- big GEMM: Wcat @ [x;pca]; Kt blocks fold e2 inline -> KtT bf16 [m][o];
//      q1 blocks emit amp/phase; kmax skips all-zero K-halves ----
__global__ __launch_bounds__(256) void k_gemm1(
    const short* __restrict__ Wcatb, const short* __restrict__ InTb,
    const float* __restrict__ angle_pca, const float* __restrict__ e2Wt,
    short* __restrict__ xqb, short* __restrict__ KtT, short* __restrict__ vsumb,
    float* __restrict__ linx, float* __restrict__ q1T)
{
    __shared__ float embs[32][65];
    __shared__ float e2ws[64][64];
    const int bid = blockIdx.x;            // 4 x 11 x 16 = 704
    const int b  = bid / 176;
    const int rt = (bid / 16) % 11;
    const int ct = bid % 16;
    const int r0 = rt*64, c0 = ct*32;
    const int w = threadIdx.x >> 6, lane = threadIdx.x & 63;
    const int lr = lane & 15, lg = lane >> 4;
    const int t = threadIdx.x;

    if (r0 == 64) {   // stage e2 operands while MFMA loads warm up
        const int mloc = t >> 3, q = t & 7;
        const float arev = angle_pca[b*512 + c0 + mloc] * FCT_REV;
        #pragma unroll
        for (int j = q*4; j < q*4+4; ++j) {
            const float arg = arev * __expf(-(float)j * DIVK);
            embs[mloc][2*j]   = sinrev(arg);
            embs[mloc][2*j+1] = cosrev(arg);
        }
        #pragma unroll
        for (int i = 0; i < 16; ++i) {
            const int idx = t + 256*i;
            e2ws[idx >> 6][idx & 63] = e2Wt[idx];
        }
    }

    const short* ap  = Wcatb + (size_t)(r0 + w*16 + lr)*512 + 8*lg;
    const short* bp0 = InTb + (size_t)b*512*512 + (size_t)(c0 + lr)*512 + 8*lg;
    const short* bp1 = bp0 + 16*512;
    // rows with zero second K-half: xq (r0==0), linx (384..639), q1 (640+)
    const int kmax = (r0 == 64 || (r0 >= 128 && r0 < 384)) ? 512 : 256;

    f32x4 acc0 = {0.f,0.f,0.f,0.f}, acc1 = {0.f,0.f,0.f,0.f};
    #pragma unroll 4
    for (int kk = 0; kk < kmax; kk += 32) {
        bf16x8 a  = *(const bf16x8*)(ap  + kk);
        bf16x8 b0 = *(const bf16x8*)(bp0 + kk);
        bf16x8 b1 = *(const bf16x8*)(bp1 + kk);
        acc0 = __builtin_amdgcn_mfma_f32_16x16x32_bf16(a, b0, acc0, 0, 0, 0);
        acc1 = __builtin_amdgcn_mfma_f32_16x16x32_bf16(a, b1, acc1, 0, 0, 0);
    }
    const int rowb = r0 + w*16 + lg*4;
    const int col0 = c0 + lr;
    if (r0 == 0) {                 // xq -> bf16 transposed [n][o]
        #pragma unroll
        for (int j = 0; j < 4; ++j) {
            xqb[((size_t)b*512 + col0)*64 + rowb + j]      = f2bf(acc0[j]);
            xqb[((size_t)b*512 + col0 + 16)*64 + rowb + j] = f2bf(acc1[j]);
        }
    } else if (r0 == 64) {         // Kt + e2 fold -> KtT bf16 [m][o]
        __syncthreads();
        const int o0 = w*16 + lg*4;
        float e[8];
        #pragma unroll
        for (int i = 0; i < 8; ++i) e[i] = 0.f;
        #pragma unroll 8
        for (int k = 0; k < 64; ++k) {
            const float em0 = embs[lr][k];
            const float em1 = embs[lr + 16][k];
            #pragma unroll
            for (int j = 0; j < 4; ++j) {
                const float wv = e2ws[k][o0 + j];
                e[j]     = fmaf(wv, em0, e[j]);
                e[4 + j] = fmaf(wv, em1, e[4 + j]);
            }
        }
        uint2 u0, u1;
        u0.x = pk2(acc0[0] + e[0], acc0[1] + e[1]);
        u0.y = pk2(acc0[2] + e[2], acc0[3] + e[3]);
        u1.x = pk2(acc1[0] + e[4], acc1[1] + e[5]);
        u1.y = pk2(acc1[2] + e[6], acc1[3] + e[7]);
        *(uint2*)(KtT + ((size_t)b*512 + col0)*64 + o0)      = u0;
        *(uint2*)(KtT + ((size_t)b*512 + col0 + 16)*64 + o0) = u1;
    } else if (r0 < 384) {         // vsum bf16 [o][n]
        #pragma unroll
        for (int j = 0; j < 4; ++j) {
            vsumb[((size_t)b*256 + rowb-128 + j)*512 + col0]      = f2bf(acc0[j]);
            vsumb[((size_t)b*256 + rowb-128 + j)*512 + col0 + 16] = f2bf(acc1[j]);
        }
    } else if (r0 < 640) {         // linW@x f32 [o][n]
        #pragma unroll
        for (int j = 0; j < 4; ++j) {
            linx[((size_t)b*256 + rowb-384 + j)*512 + col0]      = acc0[j];
            linx[((size_t)b*256 + rowb-384 + j)*512 + col0 + 16] = acc1[j];
        }
    } else {                       // q1 -> amp/phase (R, phi_rev) [n][64]
        const int off = rowb - 640;
        float* d0 = q1T + ((size_t)b*512 + col0)*64 + off;
        float* d1 = q1T + ((size_t)b*512 + col0 + 16)*64 + off;
        d0[0] = sqrtf(acc0[0]*acc0[0] + acc0[1]*acc0[1]);
        d0[1] = atan2f(acc0[1], acc0[0]) * INV2PI;
        d0[2] = sqrtf(acc0[2]*acc0[2] + acc0[3]*acc0[3]);
        d0[3] = atan2f(acc0[3], acc0[2]) * INV2PI;
        d1[0] = sqrtf(acc1[0]*acc1[0] + acc1[1]*acc1[1]);
        d1[1] = atan2f(acc1[1], acc1[0]) * INV2PI;
        d1[2] = sqrtf(acc1[2]*acc1[2] + acc1[3]*acc1[3]);
        d1[3] = atan2f(acc1[3], acc1[2]) * INV2PI;
    }
}

// ---- fused QK (LDS-staged KtT) + amp-phase energy + softmax + colsum; 4 rows/block ----
__global__ __launch_bounds__(256) void k_energy3(
    const short* __restrict__ xqb, const short* __restrict__ KtT,
    const float* __restrict__ q1T, const float* __restrict__ angle_lrf,
    short* __restrict__ ETb, float* __restrict__ colsum)
{
    __shared__ short kt[512][68];          // padded: 136B row stride -> 2-way banks
    __shared__ float xqf[4][64];
    __shared__ float qs[4][64];
    __shared__ float divs[32];
    __shared__ float4 xw[4];
    const int b  = blockIdx.x >> 7;        // 4 x 128
    const int n0 = (blockIdx.x & 127) * 4;
    const int t = threadIdx.x;
    {
        const short* src = KtT + (size_t)b*512*64;
        #pragma unroll
        for (int i = 0; i < 16; ++i) {
            const int idx = t + 256*i;          // uint4 index, 4096 total
            const int row = idx >> 3, col = (idx & 7) * 8;
            const uint4 u = *(const uint4*)(src + (size_t)row*64 + col);
            *(uint2*)&kt[row][col]     = make_uint2(u.x, u.y);
            *(uint2*)&kt[row][col + 4] = make_uint2(u.z, u.w);
        }
    }
    if (t < 64) {
        #pragma unroll
        for (int i = 0; i < 4; ++i) {
            xqf[i][t] = bf2f(xqb[((size_t)b*512 + n0 + i)*64 + t]);
            qs[i][t]  = q1T[((size_t)b*512 + n0 + i)*64 + t];
        }
    } else if (t < 96) {
        divs[t-64] = __expf(-(float)(t-64) * DIVK);
    }
    __syncthreads();
    float acc[4][2];
    #pragma unroll
    for (int i = 0; i < 4; ++i) { acc[i][0] = 0.f; acc[i][1] = 0.f; }
    for (int c = 0; c < 64; c += 4) {
        float xv[4][4];
        #pragma unroll
        for (int i = 0; i < 4; ++i) {
            #pragma unroll
            for (int j = 0; j < 4; ++j) xv[i][j] = xqf[i][c + j];
        }
        #pragma unroll
        for (int mi = 0; mi < 2; ++mi) {
            const uint2 u = *(const uint2*)&kt[t + mi*256][c];
            const float k0 = bflo(u.x), k1 = bfhi(u.x);
            const float k2 = bflo(u.y), k3 = bfhi(u.y);
            #pragma unroll
            for (int i = 0; i < 4; ++i) {
                acc[i][mi] = fmaf(k0, xv[i][0],
                             fmaf(k1, xv[i][1],
                             fmaf(k2, xv[i][2],
                             fmaf(k3, xv[i][3], acc[i][mi]))));
            }
        }
    }
    float av[4][2];
    #pragma unroll
    for (int i = 0; i < 4; ++i) {
        av[i][0] = angle_lrf[((size_t)b*512 + n0 + i)*512 + t] * FCT_REV;
        av[i][1] = angle_lrf[((size_t)b*512 + n0 + i)*512 + t + 256] * FCT_REV;
    }
    #pragma unroll 2
    for (int j = 0; j < 32; ++j) {
        const float d = divs[j];
        #pragma unroll
        for (int i = 0; i < 4; ++i) {
            const float R = qs[i][2*j], ph = qs[i][2*j+1];
            #pragma unroll
            for (int m = 0; m < 2; ++m) {
                const float arg = fmaf(av[i][m], d, ph);
                acc[i][m] = fmaf(R, sinrev(arg), acc[i][m]);
            }
        }
    }
    float v0 = fmaxf(acc[0][0], acc[0][1]), v1 = fmaxf(acc[1][0], acc[1][1]);
    float v2 = fmaxf(acc[2][0], acc[2][1]), v3 = fmaxf(acc[3][0], acc[3][1]);
    #pragma unroll
    for (int off = 1; off < 64; off <<= 1) {
        v0 = fmaxf(v0, __shfl_xor(v0, off));
        v1 = fmaxf(v1, __shfl_xor(v1, off));
        v2 = fmaxf(v2, __shfl_xor(v2, off));
        v3 = fmaxf(v3, __shfl_xor(v3, off));
    }
    const int wid = t >> 6, lane = t & 63;
    if (lane == 0) { float4 f = {v0,v1,v2,v3}; xw[wid] = f; }
    __syncthreads();
    {
        const float4 a0 = xw[0], a1 = xw[1], a2 = xw[2], a3 = xw[3];
        v0 = fmaxf(fmaxf(a0.x,a1.x), fmaxf(a2.x,a3.x));
        v1 = fmaxf(fmaxf(a0.y,a1.y), fmaxf(a2.y,a3.y));
        v2 = fmaxf(fmaxf(a0.z,a1.z), fmaxf(a2.z,a3.z));
        v3 = fmaxf(fmaxf(a0.w,a1.w), fmaxf(a2.w,a3.w));
    }
    float p[4][2];
    p[0][0] = __expf(acc[0][0]-v0); p[0][1] = __expf(acc[0][1]-v0);
    p[1][0] = __expf(acc[1][0]-v1); p[1][1] = __expf(acc[1][1]-v1);
    p[2][0] = __expf(acc[2][0]-v2); p[2][1] = __expf(acc[2][1]-v2);
    p[3][0] = __expf(acc[3][0]-v3); p[3][1] = __expf(acc[3][1]-v3);
    float s0 = p[0][0]+p[0][1], s1 = p[1][0]+p[1][1];
    float s2 = p[2][0]+p[2][1], s3 = p[3][0]+p[3][1];
    #pragma unroll
    for (int off = 1; off < 64; off <<= 1) {
        s0 += __shfl_xor(s0, off); s1 += __shfl_xor(s1, off);
        s2 += __shfl_xor(s2, off); s3 += __shfl_xor(s3, off);
    }
    __syncthreads();
    if (lane == 0) { float4 f = {s0,s1,s2,s3}; xw[wid] = f; }
    __syncthreads();
    {
        const float4 a0 = xw[0], a1 = xw[1], a2 = xw[2], a3 = xw[3];
        s0 = (a0.x+a1.x) + (a2.x+a3.x);
        s1 = (a0.y+a1.y) + (a2.y+a3.y);
        s2 = (a0.z+a1.z) + (a2.z+a3.z);
        s3 = (a0.w+a1.w) + (a2.w+a3.w);
    }
    const float i0 = 1.f/s0, i1 = 1.f/s1, i2 = 1.f/s2, i3 = 1.f/s3;
    short* Eb = ETb + (size_t)b*512*512;
    #pragma unroll
    for (int mi = 0; mi < 2; ++mi) {
        const int m = t + mi*256;
        const float e0 = p[0][mi]*i0, e1 = p[1][mi]*i1, e2 = p[2][mi]*i2, e3 = p[3][mi]*i3;
        uint2 u;
        u.x = pk2(e0, e1);
        u.y = pk2(e2, e3);
        *(uint2*)(Eb + (size_t)m*512 + n0) = u;
        atomicAdd(&colsum[b*512 + m], (e0 + e1) + (e2 + e3));
    }
}

// ---- fused xr + z: block computes all 256 o of xr for a 16-wide m slice (LDS),
//      then z = linx - linW@xr + lin_b for those m columns; + point_relation + BN stats ----
__global__ __launch_bounds__(256) void k_xrz(
    const short* __restrict__ vsumb, const short* __restrict__ ETb,
    const float* __restrict__ colsum, const short* __restrict__ Wcatb,
    const float* __restrict__ linx, const float* __restrict__ lin_b,
    float* __restrict__ z, float* __restrict__ stat, float* __restrict__ out)
{
    __shared__ short xrs[16][258];         // 516B row stride -> bank step 1
    const int bid = blockIdx.x;            // 4b x 32 mt = 128
    const int b  = bid >> 5;
    const int m0 = (bid & 31) * 16;
    const int w = threadIdx.x >> 6, lane = threadIdx.x & 63;
    const int lr = lane & 15, lg = lane >> 4;

    // ---- phase A: xr[o][m] = 0.5*rc[m] * sum_n vsum[o][n]*E[n][m]
    {
        const short* bp = ETb + (size_t)b*512*512 + (size_t)(m0 + lr)*512 + 8*lg;
        const short* ab = vsumb + (size_t)b*256*512 + 8*lg;
        f32x4 acc[4] = {{0.f,0.f,0.f,0.f},{0.f,0.f,0.f,0.f},{0.f,0.f,0.f,0.f},{0.f,0.f,0.f,0.f}};
        for (int kk = 0; kk < 512; kk += 32) {
            const bf16x8 bfrag = *(const bf16x8*)(bp + kk);
            #pragma unroll
            for (int r = 0; r < 4; ++r) {
                const bf16x8 afrag = *(const bf16x8*)(ab + (size_t)(w*64 + r*16 + lr)*512 + kk);
                acc[r] = __builtin_amdgcn_mfma_f32_16x16x32_bf16(afrag, bfrag, acc[r], 0, 0, 0);
            }
        }
        const int m = m0 + lr;
        const float sc = 0.5f / (1e-12f + colsum[b*512 + m]);
        #pragma unroll
        for (int r = 0; r < 4; ++r) {
            const int ob = w*64 + r*16 + lg*4;
            uint2 u;
            u.x = pk2(acc[r][0]*sc, acc[r][1]*sc);
            u.y = pk2(acc[r][2]*sc, acc[r][3]*sc);
            *(uint2*)&xrs[lr][ob] = u;
        }
    }
    if (w == 0 && lg == 0) {   // point_relation for this m slice
        const int m = m0 + lr;
        const float rc = 1.f / (1e-12f + colsum[b*512 + m]);
        out[(size_t)4*256*512 + b*512 + m] = bf2f(ETb[((size_t)b*512 + m)*512]) * rc;
    }
    __syncthreads();

    // ---- phase B: z[c][m] = linx[c][m] - sum_o linW[c][o]*xr[o][m] + lin_b[c]
    {
        f32x4 acc[4] = {{0.f,0.f,0.f,0.f},{0.f,0.f,0.f,0.f},{0.f,0.f,0.f,0.f},{0.f,0.f,0.f,0.f}};
        #pragma unroll
        for (int kk = 0; kk < 256; kk += 32) {
            const bf16x8 bfrag = *(const bf16x8*)&xrs[lr][8*lg + kk];
            #pragma unroll
            for (int r = 0; r < 4; ++r) {
                const short* ap = Wcatb + (size_t)(384 + w*64 + r*16 + lr)*512 + 8*lg + kk;
                acc[r] = __builtin_amdgcn_mfma_f32_16x16x32_bf16(*(const bf16x8*)ap, bfrag, acc[r], 0, 0, 0);
            }
        }
        const int col = m0 + lr;
        float* zb = z + (size_t)b*256*512;
        const float* Lb = linx + (size_t)b*256*512;
        #pragma unroll
        for (int r = 0; r < 4; ++r) {
            const int cb = w*64 + r*16 + lg*4;
            #pragma unroll
            for (int j = 0; j < 4; ++j) {
                const int c = cb + j;
                const float zv = Lb[(size_t)c*512 + col] - acc[r][j] + lin_b[c];
                zb[(size_t)c*512 + col] = zv;
                float s = zv, s2 = zv*zv;
                #pragma unroll
                for (int off = 1; off < 16; off <<= 1) {
                    s  += __shfl_xor(s,  off);
                    s2 += __shfl_xor(s2, off);
                }
                if (lr == 0) {
                    atomicAdd(&stat[c], s);
                    atomicAdd(&stat[256 + c], s2);
                }
            }
        }
    }
}

// ---- BN apply + exact gelu + residual (float4) ----
__global__ __launch_bounds__(256) void k_final(
    const float* __restrict__ x, const float* __restrict__ z,
    const float* __restrict__ stat, const float* __restrict__ gamma,
    const float* __restrict__ beta, float* __restrict__ out)
{
    const int gid = blockIdx.x*256 + threadIdx.x;   // 131072 x4 elems
    const int base = gid * 4;
    const int c = (base >> 9) & 255;
    const float mu  = stat[c] * (1.f/2048.f);
    const float var = stat[256 + c] * (1.f/2048.f) - mu*mu;
    const float gsc = gamma[c] * rsqrtf(var + 1e-5f);
    const float bt  = beta[c];
    const float4 zv = *(const float4*)&z[base];
    const float4 xv = *(const float4*)&x[base];
    float4 ov;
    {
        float y = (zv.x - mu)*gsc + bt;
        ov.x = xv.x + 0.5f*y*(1.f + erff(y*0.70710678118654752f));
        y = (zv.y - mu)*gsc + bt;
        ov.y = xv.y + 0.5f*y*(1.f + erff(y*0.70710678118654752f));
        y = (zv.z - mu)*gsc + bt;
        ov.z = xv.z + 0.5f*y*(1.f + erff(y*0.70710678118654752f));
        y = (zv.w - mu)*gsc + bt;
        ov.w = xv.w + 0.5f*y*(1.f + erff(y*0.70710678118654752f));
    }
    *(float4*)&out[base] = ov;
}

extern "C" void kernel_launch(void* const* d_in, const int* in_sizes, int n_in,
                              void* d_out, int out_size, void* d_ws, size_t ws_size,
                              hipStream_t stream)
{
    const float* x         = (const float*)d_in[0];
    const float* pca       = (const float*)d_in[1];
    const float* angle_lrf = (const float*)d_in[2];
    const float* angle_pca = (const float*)d_in[3];
    const float* Wkp       = (const float*)d_in[4];
    const float* Wk        = (const float*)d_in[5];
    const float* Wv        = (const float*)d_in[6];
    const float* Wvp       = (const float*)d_in[7];
    const float* e1W       = (const float*)d_in[8];
    const float* e2W       = (const float*)d_in[10];
    const float* linW      = (const float*)d_in[12];
    const float* linb      = (const float*)d_in[13];
    const float* gamma     = (const float*)d_in[14];
    const float* beta      = (const float*)d_in[15];

    char* w = (char*)d_ws;
    short* Wcatb  = (short*)(w + 0);          //   720896
    short* InTb   = (short*)(w + 720896);     //  2097152
    short* vsumb  = (short*)(w + 2818048);    //  1048576
    short* KtT    = (short*)(w + 3866624);    //   262144
    short* ETb    = (short*)(w + 4128768);    //  2097152
    float* stat   = (float*)(w + 7274496);    //     2048
    float* colsum = (float*)(w + 7276544);    //     8192
    float* e2Wt   = (float*)(w + 7284736);    //    16384 (dead after k_gemm1)
    float* z      = (float*)(w + 7284736);    //  2097152 (written after e2Wt last read)
    short* xqb    = (short*)(w + 12003328);   //   262144
    float* q1T    = (float*)(w + 12265472);   //   524288
    float* linx   = (float*)(w + 12789760);   //  2097152 -> end 14886912
    float* out    = (float*)d_out;

    k_prep   <<<432, 256, 0, stream>>>(Wkp, Wk, Wv, Wvp, linW, e1W, e2W, x, pca,
                                       Wcatb, InTb, e2Wt, stat, colsum);
    k_gemm1  <<<704, 256, 0, stream>>>(Wcatb, InTb, angle_pca, e2Wt,
                                       xqb, KtT, vsumb, linx, q1T);
    k_energy3<<<512, 256, 0, stream>>>(xqb, KtT, q1T, angle_lrf, ETb, colsum);
    k_xrz    <<<128, 256, 0, stream>>>(vsumb, ETb, colsum, Wcatb, linx, linb,
                                       z, stat, out);
    k_final  <<<512, 256, 0, stream>>>(x, z, stat, gamma, beta, out);
}

// Round 11
// 81.318 us; speedup vs baseline: 1.0976x; 1.0976x over previous
//
#include <hip/hip_runtime.h>
#include <math.h>

#define FCT_REV 0.6079271018540267f   // 180/(pi*15) / (2*pi)  -> revolutions
#define DIVK 0.28782313662425575f     // ln(10000)/32
#define INV2PI 0.15915494309189535f

using bf16x8 = __attribute__((ext_vector_type(8))) short;
using f32x4  = __attribute__((ext_vector_type(4))) float;

__device__ inline short f2bf(float f) {
    union { float f; unsigned u; } v; v.f = f;
    unsigned r = v.u + 0x7FFFu + ((v.u >> 16) & 1u);
    return (short)(r >> 16);
}
__device__ inline float bf2f(short s) {
    union { unsigned u; float f; } v;
    v.u = ((unsigned)(unsigned short)s) << 16;
    return v.f;
}
__device__ inline float bflo(unsigned u) {
    union { unsigned q; float f; } v; v.q = u << 16; return v.f;
}
__device__ inline float bfhi(unsigned u) {
    union { unsigned q; float f; } v; v.q = u & 0xFFFF0000u; return v.f;
}
__device__ inline unsigned pk2(float lo, float hi) {
    return ((unsigned)(unsigned short)f2bf(hi) << 16) | (unsigned)(unsigned short)f2bf(lo);
}
__device__ inline float sinrev(float x) {  // sin(2*pi*x)
    float r; asm("v_sin_f32 %0, %1" : "=v"(r) : "v"(x)); return r;
}
__device__ inline float cosrev(float x) {  // cos(2*pi*x)
    float r; asm("v_cos_f32 %0, %1" : "=v"(r) : "v"(x)); return r;
}

// ---- prep: Wcat bf16 [704][512] + InT bf16 [b][n][k] + e2Wt[k][o] + zero stat/colsum ----
__global__ __launch_bounds__(256) void k_prep(
    const float* __restrict__ Wkp, const float* __restrict__ Wk,
    const float* __restrict__ Wv, const float* __restrict__ Wvp,
    const float* __restrict__ linW, const float* __restrict__ e1W,
    const float* __restrict__ e2W,
    const float* __restrict__ x, const float* __restrict__ pca,
    short* __restrict__ Wcatb, short* __restrict__ InTb,
    float* __restrict__ e2Wt, float* __restrict__ stat, float* __restrict__ colsum)
{
    __shared__ float ts[64][65];
    const int bid = blockIdx.x;
    const int t = threadIdx.x;
    if (bid < 176) {
        if (bid == 0) {
            for (int i = t; i < 2048; i += 256) colsum[i] = 0.f;
            for (int i = t; i < 512; i += 256) stat[i] = 0.f;
        } else if (bid == 1) {
            for (int i = t; i < 4096; i += 256) {
                int k = i >> 6, o = i & 63;
                e2Wt[k*64 + o] = e2W[o*64 + k];
            }
        }
        #pragma unroll
        for (int rr = 0; rr < 4; ++rr) {
            const int r = bid*4 + rr;
            for (int k = t; k < 512; k += 256) {
                float v = 0.f;
                if (r < 64) { if (k < 256) v = Wkp[r*256 + k]; }
                else if (r < 128) { int o = r-64;  v = (k<256) ? Wk[o*256+k]  : Wkp[o*256 + k-256]; }
                else if (r < 384) { int o = r-128; v = (k<256) ? Wv[o*256+k]  : Wvp[o*256 + k-256]; }
                else if (r < 640) { int o = r-384; if (k<256) v = linW[o*256+k]; }
                else {
                    int o = r-640;
                    if (k < 256) {
                        float a = 0.f;
                        for (int j = 0; j < 64; ++j) a = fmaf(e1W[j*64 + o], Wkp[j*256 + k], a);
                        v = a;
                    }
                }
                Wcatb[(size_t)r*512 + k] = f2bf(v);
            }
        }
    } else {
        const int id = bid - 176;             // 4b x 8kt x 8nt
        const int b  = id >> 6;
        const int kt = (id >> 3) & 7;
        const int nt = id & 7;
        const int k0 = kt*64, n0 = nt*64;
        const float* src = (k0 < 256) ? (x + ((size_t)b*256 + k0)*512)
                                      : (pca + ((size_t)b*256 + (k0-256))*512);
        #pragma unroll
        for (int i = 0; i < 16; ++i) {
            int idx = t + 256*i;
            int r = idx >> 6, c = idx & 63;
            ts[r][c] = src[(size_t)r*512 + n0 + c];
        }
        __syncthreads();
        short* dst = InTb + (size_t)b*512*512;
        #pragma unroll
        for (int i = 0; i < 16; ++i) {
            int idx = t + 256*i;
            int n = idx >> 6, k = idx & 63;
            dst[(size_t)(n0+n)*512 + k0 + k] = f2bf(ts[k][n]);
        }
    }
}

// ---- big GEMM: Wcat @ [x;pca]; Kt blocks fold e2 inline -> KtT bf16 [m][o];
//      q1 blocks emit amp/phase; kmax skips all-zero K-halves ----
__global__ __launch_bounds__(256) void k_gemm1(
    const short* __restrict__ Wcatb, const short* __restrict__ InTb,
    const float* __restrict__ angle_pca, const float* __restrict__ e2Wt,
    short* __restrict__ xqb, short* __restrict__ KtT, short* __restrict__ vsumb,
    float* __restrict__ linx, float* __restrict__ q1T)
{
    __shared__ float embs[32][65];
    __shared__ float e2ws[64][64];
    const int bid = blockIdx.x;            // 4 x 11 x 16 = 704
    const int b  = bid / 176;
    const int rt = (bid / 16) % 11;
    const int ct = bid % 16;
    const int r0 = rt*64, c0 = ct*32;
    const int w = threadIdx.x >> 6, lane = threadIdx.x & 63;
    const int lr = lane & 15, lg = lane >> 4;
    const int t = threadIdx.x;

    if (r0 == 64) {   // stage e2 operands while MFMA loads warm up
        const int mloc = t >> 3, q = t & 7;
        const float arev = angle_pca[b*512 + c0 + mloc] * FCT_REV;
        #pragma unroll
        for (int j = q*4; j < q*4+4; ++j) {
            const float arg = arev * __expf(-(float)j * DIVK);
            embs[mloc][2*j]   = sinrev(arg);
            embs[mloc][2*j+1] = cosrev(arg);
        }
        #pragma unroll
        for (int i = 0; i < 16; ++i) {
            const int idx = t + 256*i;
            e2ws[idx >> 6][idx & 63] = e2Wt[idx];
        }
    }

    const short* ap  = Wcatb + (size_t)(r0 + w*16 + lr)*512 + 8*lg;
    const short* bp0 = InTb + (size_t)b*512*512 + (size_t)(c0 + lr)*512 + 8*lg;
    const short* bp1 = bp0 + 16*512;
    // rows with zero second K-half: xq (r0==0), linx (384..639), q1 (640+)
    const int kmax = (r0 == 64 || (r0 >= 128 && r0 < 384)) ? 512 : 256;

    f32x4 acc0 = {0.f,0.f,0.f,0.f}, acc1 = {0.f,0.f,0.f,0.f};
    #pragma unroll 4
    for (int kk = 0; kk < kmax; kk += 32) {
        bf16x8 a  = *(const bf16x8*)(ap  + kk);
        bf16x8 b0 = *(const bf16x8*)(bp0 + kk);
        bf16x8 b1 = *(const bf16x8*)(bp1 + kk);
        acc0 = __builtin_amdgcn_mfma_f32_16x16x32_bf16(a, b0, acc0, 0, 0, 0);
        acc1 = __builtin_amdgcn_mfma_f32_16x16x32_bf16(a, b1, acc1, 0, 0, 0);
    }
    const int rowb = r0 + w*16 + lg*4;
    const int col0 = c0 + lr;
    if (r0 == 0) {                 // xq -> bf16 transposed [n][o]
        #pragma unroll
        for (int j = 0; j < 4; ++j) {
            xqb[((size_t)b*512 + col0)*64 + rowb + j]      = f2bf(acc0[j]);
            xqb[((size_t)b*512 + col0 + 16)*64 + rowb + j] = f2bf(acc1[j]);
        }
    } else if (r0 == 64) {         // Kt + e2 fold -> KtT bf16 [m][o]
        __syncthreads();
        const int o0 = w*16 + lg*4;
        float e[8];
        #pragma unroll
        for (int i = 0; i < 8; ++i) e[i] = 0.f;
        #pragma unroll 8
        for (int k = 0; k < 64; ++k) {
            const float em0 = embs[lr][k];
            const float em1 = embs[lr + 16][k];
            #pragma unroll
            for (int j = 0; j < 4; ++j) {
                const float wv = e2ws[k][o0 + j];
                e[j]     = fmaf(wv, em0, e[j]);
                e[4 + j] = fmaf(wv, em1, e[4 + j]);
            }
        }
        uint2 u0, u1;
        u0.x = pk2(acc0[0] + e[0], acc0[1] + e[1]);
        u0.y = pk2(acc0[2] + e[2], acc0[3] + e[3]);
        u1.x = pk2(acc1[0] + e[4], acc1[1] + e[5]);
        u1.y = pk2(acc1[2] + e[6], acc1[3] + e[7]);
        *(uint2*)(KtT + ((size_t)b*512 + col0)*64 + o0)      = u0;
        *(uint2*)(KtT + ((size_t)b*512 + col0 + 16)*64 + o0) = u1;
    } else if (r0 < 384) {         // vsum bf16 [o][n]
        #pragma unroll
        for (int j = 0; j < 4; ++j) {
            vsumb[((size_t)b*256 + rowb-128 + j)*512 + col0]      = f2bf(acc0[j]);
            vsumb[((size_t)b*256 + rowb-128 + j)*512 + col0 + 16] = f2bf(acc1[j]);
        }
    } else if (r0 < 640) {         // linW@x f32 [o][n]
        #pragma unroll
        for (int j = 0; j < 4; ++j) {
            linx[((size_t)b*256 + rowb-384 + j)*512 + col0]      = acc0[j];
            linx[((size_t)b*256 + rowb-384 + j)*512 + col0 + 16] = acc1[j];
        }
    } else {                       // q1 -> amp/phase (R, phi_rev) [n][64]
        const int off = rowb - 640;
        float* d0 = q1T + ((size_t)b*512 + col0)*64 + off;
        float* d1 = q1T + ((size_t)b*512 + col0 + 16)*64 + off;
        d0[0] = sqrtf(acc0[0]*acc0[0] + acc0[1]*acc0[1]);
        d0[1] = atan2f(acc0[1], acc0[0]) * INV2PI;
        d0[2] = sqrtf(acc0[2]*acc0[2] + acc0[3]*acc0[3]);
        d0[3] = atan2f(acc0[3], acc0[2]) * INV2PI;
        d1[0] = sqrtf(acc1[0]*acc1[0] + acc1[1]*acc1[1]);
        d1[1] = atan2f(acc1[1], acc1[0]) * INV2PI;
        d1[2] = sqrtf(acc1[2]*acc1[2] + acc1[3]*acc1[3]);
        d1[3] = atan2f(acc1[3], acc1[2]) * INV2PI;
    }
}

// ---- fused QK (LDS-staged KtT) + amp-phase energy + softmax + colsum; 4 rows/block ----
__global__ __launch_bounds__(256) void k_energy3(
    const short* __restrict__ xqb, const short* __restrict__ KtT,
    const float* __restrict__ q1T, const float* __restrict__ angle_lrf,
    short* __restrict__ ETb, float* __restrict__ colsum)
{
    __shared__ short kt[512][68];          // padded: 136B row stride -> 2-way banks
    __shared__ float xqf[4][64];
    __shared__ float qs[4][64];
    __shared__ float divs[32];
    __shared__ float4 xw[4];
    const int b  = blockIdx.x >> 7;        // 4 x 128
    const int n0 = (blockIdx.x & 127) * 4;
    const int t = threadIdx.x;
    {
        const short* src = KtT + (size_t)b*512*64;
        #pragma unroll
        for (int i = 0; i < 16; ++i) {
            const int idx = t + 256*i;          // uint4 index, 4096 total
            const int row = idx >> 3, col = (idx & 7) * 8;
            const uint4 u = *(const uint4*)(src + (size_t)row*64 + col);
            *(uint2*)&kt[row][col]     = make_uint2(u.x, u.y);
            *(uint2*)&kt[row][col + 4] = make_uint2(u.z, u.w);
        }
    }
    if (t < 64) {
        #pragma unroll
        for (int i = 0; i < 4; ++i) {
            xqf[i][t] = bf2f(xqb[((size_t)b*512 + n0 + i)*64 + t]);
            qs[i][t]  = q1T[((size_t)b*512 + n0 + i)*64 + t];
        }
    } else if (t < 96) {
        divs[t-64] = __expf(-(float)(t-64) * DIVK);
    }
    __syncthreads();
    float acc[4][2];
    #pragma unroll
    for (int i = 0; i < 4; ++i) { acc[i][0] = 0.f; acc[i][1] = 0.f; }
    for (int c = 0; c < 64; c += 4) {
        float xv[4][4];
        #pragma unroll
        for (int i = 0; i < 4; ++i) {
            #pragma unroll
            for (int j = 0; j < 4; ++j) xv[i][j] = xqf[i][c + j];
        }
        #pragma unroll
        for (int mi = 0; mi < 2; ++mi) {
            const uint2 u = *(const uint2*)&kt[t + mi*256][c];
            const float k0 = bflo(u.x), k1 = bfhi(u.x);
            const float k2 = bflo(u.y), k3 = bfhi(u.y);
            #pragma unroll
            for (int i = 0; i < 4; ++i) {
                acc[i][mi] = fmaf(k0, xv[i][0],
                             fmaf(k1, xv[i][1],
                             fmaf(k2, xv[i][2],
                             fmaf(k3, xv[i][3], acc[i][mi]))));
            }
        }
    }
    float av[4][2];
    #pragma unroll
    for (int i = 0; i < 4; ++i) {
        av[i][0] = angle_lrf[((size_t)b*512 + n0 + i)*512 + t] * FCT_REV;
        av[i][1] = angle_lrf[((size_t)b*512 + n0 + i)*512 + t + 256] * FCT_REV;
    }
    #pragma unroll 2
    for (int j = 0; j < 32; ++j) {
        const float d = divs[j];
        #pragma unroll
        for (int i = 0; i < 4; ++i) {
            const float R = qs[i][2*j], ph = qs[i][2*j+1];
            #pragma unroll
            for (int m = 0; m < 2; ++m) {
                const float arg = fmaf(av[i][m], d, ph);
                acc[i][m] = fmaf(R, sinrev(arg), acc[i][m]);
            }
        }
    }
    float v0 = fmaxf(acc[0][0], acc[0][1]), v1 = fmaxf(acc[1][0], acc[1][1]);
    float v2 = fmaxf(acc[2][0], acc[2][1]), v3 = fmaxf(acc[3][0], acc[3][1]);
    #pragma unroll
    for (int off = 1; off < 64; off <<= 1) {
        v0 = fmaxf(v0, __shfl_xor(v0, off));
        v1 = fmaxf(v1, __shfl_xor(v1, off));
        v2 = fmaxf(v2, __shfl_xor(v2, off));
        v3 = fmaxf(v3, __shfl_xor(v3, off));
    }
    const int wid = t >> 6, lane = t & 63;
    if (lane == 0) { float4 f = {v0,v1,v2,v3}; xw[wid] = f; }
    __syncthreads();
    {
        const float4 a0 = xw[0], a1 = xw[1], a2 = xw[2], a3 = xw[3];
        v0 = fmaxf(fmaxf(a0.x,a1.x), fmaxf(a2.x,a3.x));
        v1 = fmaxf(fmaxf(a0.y,a1.y), fmaxf(a2.y,a3.y));
        v2 = fmaxf(fmaxf(a0.z,a1.z), fmaxf(a2.z,a3.z));
        v3 = fmaxf(fmaxf(a0.w,a1.w), fmaxf(a2.w,a3.w));
    }
    float p[4][2];
    p[0][0] = __expf(acc[0][0]-v0); p[0][1] = __expf(acc[0][1]-v0);
    p[1][0] = __expf(acc[1][0]-v1); p[1][1] = __expf(acc[1][1]-v1);
    p[2][0] = __expf(acc[2][0]-v2); p[2][1] = __expf(acc[2][1]-v2);
    p[3][0] = __expf(acc[3][0]-v3); p[3][1] = __expf(acc[3][1]-v3);
    float s0 = p[0][0]+p[0][1], s1 = p[1][0]+p[1][1];
    float s2 = p[2][0]+p[2][1], s3 = p[3][0]+p[3][1];
    #pragma unroll
    for (int off = 1; off < 64; off <<= 1) {
        s0 += __shfl_xor(s0, off); s1 += __shfl_xor(s1, off);
        s2 += __shfl_xor(s2, off); s3 += __shfl_xor(s3, off);
    }
    __syncthreads();
    if (lane == 0) { float4 f = {s0,s1,s2,s3}; xw[wid] = f; }
    __syncthreads();
    {
        const float4 a0 = xw[0], a1 = xw[1], a2 = xw[2], a3 = xw[3];
        s0 = (a0.x+a1.x) + (a2.x+a3.x);
        s1 = (a0.y+a1.y) + (a2.y+a3.y);
        s2 = (a0.z+a1.z) + (a2.z+a3.z);
        s3 = (a0.w+a1.w) + (a2.w+a3.w);
    }
    const float i0 = 1.f/s0, i1 = 1.f/s1, i2 = 1.f/s2, i3 = 1.f/s3;
    short* Eb = ETb + (size_t)b*512*512;
    #pragma unroll
    for (int mi = 0; mi < 2; ++mi) {
        const int m = t + mi*256;
        const float e0 = p[0][mi]*i0, e1 = p[1][mi]*i1, e2 = p[2][mi]*i2, e3 = p[3][mi]*i3;
        uint2 u;
        u.x = pk2(e0, e1);
        u.y = pk2(e2, e3);
        *(uint2*)(Eb + (size_t)m*512 + n0) = u;
        atomicAdd(&colsum[b*512 + m], (e0 + e1) + (e2 + e3));
    }
}

// ---- fused xr + z, grid 256: block (b, mt, ch). Phase A: full xr for 16-m slice
//      (duplicated across the 2 ch blocks, cheap); phase B: z for 128 c-rows. ----
__global__ __launch_bounds__(256) void k_xrz(
    const short* __restrict__ vsumb, const short* __restrict__ ETb,
    const float* __restrict__ colsum, const short* __restrict__ Wcatb,
    const float* __restrict__ linx, const float* __restrict__ lin_b,
    float* __restrict__ z, float* __restrict__ stat, float* __restrict__ out)
{
    __shared__ short xrs[16][260];         // 520B row stride: 8B-aligned, bank step 2 (free)
    const int bid = blockIdx.x;            // 4b x 32mt x 2ch = 256
    const int b  = bid >> 6;
    const int m0 = ((bid >> 1) & 31) * 16;
    const int ch = bid & 1;
    const int w = threadIdx.x >> 6, lane = threadIdx.x & 63;
    const int lr = lane & 15, lg = lane >> 4;

    // ---- phase A: xr[o][m] = 0.5*rc[m] * sum_n vsum[o][n]*E[n][m]  (all 256 o)
    {
        const short* bp = ETb + (size_t)b*512*512 + (size_t)(m0 + lr)*512 + 8*lg;
        const short* ab = vsumb + (size_t)b*256*512 + 8*lg;
        f32x4 acc[4] = {{0.f,0.f,0.f,0.f},{0.f,0.f,0.f,0.f},{0.f,0.f,0.f,0.f},{0.f,0.f,0.f,0.f}};
        for (int kk = 0; kk < 512; kk += 32) {
            const bf16x8 bfrag = *(const bf16x8*)(bp + kk);
            #pragma unroll
            for (int r = 0; r < 4; ++r) {
                const bf16x8 afrag = *(const bf16x8*)(ab + (size_t)(w*64 + r*16 + lr)*512 + kk);
                acc[r] = __builtin_amdgcn_mfma_f32_16x16x32_bf16(afrag, bfrag, acc[r], 0, 0, 0);
            }
        }
        const int m = m0 + lr;
        const float sc = 0.5f / (1e-12f + colsum[b*512 + m]);
        #pragma unroll
        for (int r = 0; r < 4; ++r) {
            const int ob = w*64 + r*16 + lg*4;
            uint2 u;
            u.x = pk2(acc[r][0]*sc, acc[r][1]*sc);
            u.y = pk2(acc[r][2]*sc, acc[r][3]*sc);
            *(uint2*)&xrs[lr][ob] = u;
        }
    }
    if (ch == 0 && w == 0 && lg == 0) {   // point_relation for this m slice (once)
        const int m = m0 + lr;
        const float rc = 1.f / (1e-12f + colsum[b*512 + m]);
        out[(size_t)4*256*512 + b*512 + m] = bf2f(ETb[((size_t)b*512 + m)*512]) * rc;
    }
    __syncthreads();

    // ---- phase B: z[c][m] = linx[c][m] - sum_o linW[c][o]*xr[o][m] + lin_b[c]
    //      this block handles c in [ch*128, ch*128+128)
    {
        f32x4 acc[2] = {{0.f,0.f,0.f,0.f},{0.f,0.f,0.f,0.f}};
        #pragma unroll
        for (int kk = 0; kk < 256; kk += 32) {
            const bf16x8 bfrag = *(const bf16x8*)&xrs[lr][8*lg + kk];
            #pragma unroll
            for (int r = 0; r < 2; ++r) {
                const short* ap = Wcatb + (size_t)(384 + ch*128 + w*32 + r*16 + lr)*512 + 8*lg + kk;
                acc[r] = __builtin_amdgcn_mfma_f32_16x16x32_bf16(*(const bf16x8*)ap, bfrag, acc[r], 0, 0, 0);
            }
        }
        const int col = m0 + lr;
        float* zb = z + (size_t)b*256*512;
        const float* Lb = linx + (size_t)b*256*512;
        #pragma unroll
        for (int r = 0; r < 2; ++r) {
            const int cb = ch*128 + w*32 + r*16 + lg*4;
            #pragma unroll
            for (int j = 0; j < 4; ++j) {
                const int c = cb + j;
                const float zv = Lb[(size_t)c*512 + col] - acc[r][j] + lin_b[c];
                zb[(size_t)c*512 + col] = zv;
                float s = zv, s2 = zv*zv;
                #pragma unroll
                for (int off = 1; off < 16; off <<= 1) {
                    s  += __shfl_xor(s,  off);
                    s2 += __shfl_xor(s2, off);
                }
                if (lr == 0) {
                    atomicAdd(&stat[c], s);
                    atomicAdd(&stat[256 + c], s2);
                }
            }
        }
    }
}

// ---- BN apply + exact gelu + residual (float4) ----
__global__ __launch_bounds__(256) void k_final(
    const float* __restrict__ x, const float* __restrict__ z,
    const float* __restrict__ stat, const float* __restrict__ gamma,
    const float* __restrict__ beta, float* __restrict__ out)
{
    const int gid = blockIdx.x*256 + threadIdx.x;   // 131072 x4 elems
    const int base = gid * 4;
    const int c = (base >> 9) & 255;
    const float mu  = stat[c] * (1.f/2048.f);
    const float var = stat[256 + c] * (1.f/2048.f) - mu*mu;
    const float gsc = gamma[c] * rsqrtf(var + 1e-5f);
    const float bt  = beta[c];
    const float4 zv = *(const float4*)&z[base];
    const float4 xv = *(const float4*)&x[base];
    float4 ov;
    {
        float y = (zv.x - mu)*gsc + bt;
        ov.x = xv.x + 0.5f*y*(1.f + erff(y*0.70710678118654752f));
        y = (zv.y - mu)*gsc + bt;
        ov.y = xv.y + 0.5f*y*(1.f + erff(y*0.70710678118654752f));
        y = (zv.z - mu)*gsc + bt;
        ov.z = xv.z + 0.5f*y*(1.f + erff(y*0.70710678118654752f));
        y = (zv.w - mu)*gsc + bt;
        ov.w = xv.w + 0.5f*y*(1.f + erff(y*0.70710678118654752f));
    }
    *(float4*)&out[base] = ov;
}

extern "C" void kernel_launch(void* const* d_in, const int* in_sizes, int n_in,
                              void* d_out, int out_size, void* d_ws, size_t ws_size,
                              hipStream_t stream)
{
    const float* x         = (const float*)d_in[0];
    const float* pca       = (const float*)d_in[1];
    const float* angle_lrf = (const float*)d_in[2];
    const float* angle_pca = (const float*)d_in[3];
    const float* Wkp       = (const float*)d_in[4];
    const float* Wk        = (const float*)d_in[5];
    const float* Wv        = (const float*)d_in[6];
    const float* Wvp       = (const float*)d_in[7];
    const float* e1W       = (const float*)d_in[8];
    const float* e2W       = (const float*)d_in[10];
    const float* linW      = (const float*)d_in[12];
    const float* linb      = (const float*)d_in[13];
    const float* gamma     = (const float*)d_in[14];
    const float* beta      = (const float*)d_in[15];

    char* w = (char*)d_ws;
    short* Wcatb  = (short*)(w + 0);          //   720896
    short* InTb   = (short*)(w + 720896);     //  2097152
    short* vsumb  = (short*)(w + 2818048);    //  1048576
    short* KtT    = (short*)(w + 3866624);    //   262144
    short* ETb    = (short*)(w + 4128768);    //  2097152
    float* stat   = (float*)(w + 7274496);    //     2048
    float* colsum = (float*)(w + 7276544);    //     8192
    float* e2Wt   = (float*)(w + 7284736);    //    16384 (dead after k_gemm1)
    float* z      = (float*)(w + 7284736);    //  2097152 (written after e2Wt last read)
    short* xqb    = (short*)(w + 12003328);   //   262144
    float* q1T    = (float*)(w + 12265472);   //   524288
    float* linx   = (float*)(w + 12789760);   //  2097152 -> end 14886912
    float* out    = (float*)d_out;

    k_prep   <<<432, 256, 0, stream>>>(Wkp, Wk, Wv, Wvp, linW, e1W, e2W, x, pca,
                                       Wcatb, InTb, e2Wt, stat, colsum);
    k_gemm1  <<<704, 256, 0, stream>>>(Wcatb, InTb, angle_pca, e2Wt,
                                       xqb, KtT, vsumb, linx, q1T);
    k_energy3<<<512, 256, 0, stream>>>(xqb, KtT, q1T, angle_lrf, ETb, colsum);
    k_xrz    <<<256, 256, 0, stream>>>(vsumb, ETb, colsum, Wcatb, linx, linb,
                                       z, stat, out);
    k_final  <<<512, 256, 0, stream>>>(x, z, stat, gamma, beta, out);
}

// Round 12
// 73.192 us; speedup vs baseline: 1.2195x; 1.1110x over previous
//
#include <hip/hip_runtime.h>
#include <math.h>

#define FCT_REV 0.6079271018540267f   // 180/(pi*15) / (2*pi)  -> revolutions
#define DIVK 0.28782313662425575f     // ln(10000)/32
#define INV2PI 0.15915494309189535f

using bf16x8 = __attribute__((ext_vector_type(8))) short;
using f32x4  = __attribute__((ext_vector_type(4))) float;

__device__ inline short f2bf(float f) {
    union { float f; unsigned u; } v; v.f = f;
    unsigned r = v.u + 0x7FFFu + ((v.u >> 16) & 1u);
    return (short)(r >> 16);
}
__device__ inline float bf2f(short s) {
    union { unsigned u; float f; } v;
    v.u = ((unsigned)(unsigned short)s) << 16;
    return v.f;
}
__device__ inline float bflo(unsigned u) {
    union { unsigned q; float f; } v; v.q = u << 16; return v.f;
}
__device__ inline float bfhi(unsigned u) {
    union { unsigned q; float f; } v; v.q = u & 0xFFFF0000u; return v.f;
}
__device__ inline unsigned pk2(float lo, float hi) {
    return ((unsigned)(unsigned short)f2bf(hi) << 16) | (unsigned)(unsigned short)f2bf(lo);
}
__device__ inline float sinrev(float x) {  // sin(2*pi*x)
    float r; asm("v_sin_f32 %0, %1" : "=v"(r) : "v"(x)); return r;
}
__device__ inline float cosrev(float x) {  // cos(2*pi*x)
    float r; asm("v_cos_f32 %0, %1" : "=v"(r) : "v"(x)); return r;
}

// ---- prep: Wcat bf16 [704][512] + InT bf16 [b][n][k] + e2Wt[k][o] + zero stat/colsum ----
__global__ __launch_bounds__(256) void k_prep(
    const float* __restrict__ Wkp, const float* __restrict__ Wk,
    const float* __restrict__ Wv, const float* __restrict__ Wvp,
    const float* __restrict__ linW, const float* __restrict__ e1W,
    const float* __restrict__ e2W,
    const float* __restrict__ x, const float* __restrict__ pca,
    short* __restrict__ Wcatb, short* __restrict__ InTb,
    float* __restrict__ e2Wt, float* __restrict__ stat, float* __restrict__ colsum)
{
    __shared__ float ts[64][65];
    const int bid = blockIdx.x;
    const int t = threadIdx.x;
    if (bid < 176) {
        if (bid == 0) {
            for (int i = t; i < 2048; i += 256) colsum[i] = 0.f;
            for (int i = t; i < 512; i += 256) stat[i] = 0.f;
        } else if (bid == 1) {
            for (int i = t; i < 4096; i += 256) {
                int k = i >> 6, o = i & 63;
                e2Wt[k*64 + o] = e2W[o*64 + k];
            }
        }
        #pragma unroll
        for (int rr = 0; rr < 4; ++rr) {
            const int r = bid*4 + rr;
            for (int k = t; k < 512; k += 256) {
                float v = 0.f;
                if (r < 64) { if (k < 256) v = Wkp[r*256 + k]; }
                else if (r < 128) { int o = r-64;  v = (k<256) ? Wk[o*256+k]  : Wkp[o*256 + k-256]; }
                else if (r < 384) { int o = r-128; v = (k<256) ? Wv[o*256+k]  : Wvp[o*256 + k-256]; }
                else if (r < 640) { int o = r-384; if (k<256) v = linW[o*256+k]; }
                else {
                    int o = r-640;
                    if (k < 256) {
                        float a = 0.f;
                        for (int j = 0; j < 64; ++j) a = fmaf(e1W[j*64 + o], Wkp[j*256 + k], a);
                        v = a;
                    }
                }
                Wcatb[(size_t)r*512 + k] = f2bf(v);
            }
        }
    } else {
        const int id = bid - 176;             // 4b x 8kt x 8nt
        const int b  = id >> 6;
        const int kt = (id >> 3) & 7;
        const int nt = id & 7;
        const int k0 = kt*64, n0 = nt*64;
        const float* src = (k0 < 256) ? (x + ((size_t)b*256 + k0)*512)
                                      : (pca + ((size_t)b*256 + (k0-256))*512);
        #pragma unroll
        for (int i = 0; i < 16; ++i) {
            int idx = t + 256*i;
            int r = idx >> 6, c = idx & 63;
            ts[r][c] = src[(size_t)r*512 + n0 + c];
        }
        __syncthreads();
        short* dst = InTb + (size_t)b*512*512;
        #pragma unroll
        for (int i = 0; i < 16; ++i) {
            int idx = t + 256*i;
            int n = idx >> 6, k = idx & 63;
            dst[(size_t)(n0+n)*512 + k0 + k] = f2bf(ts[k][n]);
        }
    }
}

// ---- big GEMM: Wcat @ [x;pca]; Kt blocks fold e2 inline -> KtT bf16 [m][o];
//      q1 blocks emit amp/phase; kmax skips all-zero K-halves ----
__global__ __launch_bounds__(256) void k_gemm1(
    const short* __restrict__ Wcatb, const short* __restrict__ InTb,
    const float* __restrict__ angle_pca, const float* __restrict__ e2Wt,
    short* __restrict__ xqb, short* __restrict__ KtT, short* __restrict__ vsumb,
    float* __restrict__ linx, float* __restrict__ q1T)
{
    __shared__ float embs[32][65];
    __shared__ float e2ws[64][64];
    const int bid = blockIdx.x;            // 4 x 11 x 16 = 704
    const int b  = bid / 176;
    const int rt = (bid / 16) % 11;
    const int ct = bid % 16;
    const int r0 = rt*64, c0 = ct*32;
    const int w = threadIdx.x >> 6, lane = threadIdx.x & 63;
    const int lr = lane & 15, lg = lane >> 4;
    const int t = threadIdx.x;

    if (r0 == 64) {   // stage e2 operands while MFMA loads warm up
        const int mloc = t >> 3, q = t & 7;
        const float arev = angle_pca[b*512 + c0 + mloc] * FCT_REV;
        #pragma unroll
        for (int j = q*4; j < q*4+4; ++j) {
            const float arg = arev * __expf(-(float)j * DIVK);
            embs[mloc][2*j]   = sinrev(arg);
            embs[mloc][2*j+1] = cosrev(arg);
        }
        #pragma unroll
        for (int i = 0; i < 16; ++i) {
            const int idx = t + 256*i;
            e2ws[idx >> 6][idx & 63] = e2Wt[idx];
        }
    }

    const short* ap  = Wcatb + (size_t)(r0 + w*16 + lr)*512 + 8*lg;
    const short* bp0 = InTb + (size_t)b*512*512 + (size_t)(c0 + lr)*512 + 8*lg;
    const short* bp1 = bp0 + 16*512;
    // rows with zero second K-half: xq (r0==0), linx (384..639), q1 (640+)
    const int kmax = (r0 == 64 || (r0 >= 128 && r0 < 384)) ? 512 : 256;

    f32x4 acc0 = {0.f,0.f,0.f,0.f}, acc1 = {0.f,0.f,0.f,0.f};
    #pragma unroll 4
    for (int kk = 0; kk < kmax; kk += 32) {
        bf16x8 a  = *(const bf16x8*)(ap  + kk);
        bf16x8 b0 = *(const bf16x8*)(bp0 + kk);
        bf16x8 b1 = *(const bf16x8*)(bp1 + kk);
        acc0 = __builtin_amdgcn_mfma_f32_16x16x32_bf16(a, b0, acc0, 0, 0, 0);
        acc1 = __builtin_amdgcn_mfma_f32_16x16x32_bf16(a, b1, acc1, 0, 0, 0);
    }
    const int rowb = r0 + w*16 + lg*4;
    const int col0 = c0 + lr;
    if (r0 == 0) {                 // xq -> bf16 transposed [n][o]
        #pragma unroll
        for (int j = 0; j < 4; ++j) {
            xqb[((size_t)b*512 + col0)*64 + rowb + j]      = f2bf(acc0[j]);
            xqb[((size_t)b*512 + col0 + 16)*64 + rowb + j] = f2bf(acc1[j]);
        }
    } else if (r0 == 64) {         // Kt + e2 fold -> KtT bf16 [m][o]
        __syncthreads();
        const int o0 = w*16 + lg*4;
        float e[8];
        #pragma unroll
        for (int i = 0; i < 8; ++i) e[i] = 0.f;
        #pragma unroll 8
        for (int k = 0; k < 64; ++k) {
            const float em0 = embs[lr][k];
            const float em1 = embs[lr + 16][k];
            #pragma unroll
            for (int j = 0; j < 4; ++j) {
                const float wv = e2ws[k][o0 + j];
                e[j]     = fmaf(wv, em0, e[j]);
                e[4 + j] = fmaf(wv, em1, e[4 + j]);
            }
        }
        uint2 u0, u1;
        u0.x = pk2(acc0[0] + e[0], acc0[1] + e[1]);
        u0.y = pk2(acc0[2] + e[2], acc0[3] + e[3]);
        u1.x = pk2(acc1[0] + e[4], acc1[1] + e[5]);
        u1.y = pk2(acc1[2] + e[6], acc1[3] + e[7]);
        *(uint2*)(KtT + ((size_t)b*512 + col0)*64 + o0)      = u0;
        *(uint2*)(KtT + ((size_t)b*512 + col0 + 16)*64 + o0) = u1;
    } else if (r0 < 384) {         // vsum bf16 [o][n]
        #pragma unroll
        for (int j = 0; j < 4; ++j) {
            vsumb[((size_t)b*256 + rowb-128 + j)*512 + col0]      = f2bf(acc0[j]);
            vsumb[((size_t)b*256 + rowb-128 + j)*512 + col0 + 16] = f2bf(acc1[j]);
        }
    } else if (r0 < 640) {         // linW@x f32 [o][n]
        #pragma unroll
        for (int j = 0; j < 4; ++j) {
            linx[((size_t)b*256 + rowb-384 + j)*512 + col0]      = acc0[j];
            linx[((size_t)b*256 + rowb-384 + j)*512 + col0 + 16] = acc1[j];
        }
    } else {                       // q1 -> amp/phase (R, phi_rev) [n][64]
        const int off = rowb - 640;
        float* d0 = q1T + ((size_t)b*512 + col0)*64 + off;
        float* d1 = q1T + ((size_t)b*512 + col0 + 16)*64 + off;
        d0[0] = sqrtf(acc0[0]*acc0[0] + acc0[1]*acc0[1]);
        d0[1] = atan2f(acc0[1], acc0[0]) * INV2PI;
        d0[2] = sqrtf(acc0[2]*acc0[2] + acc0[3]*acc0[3]);
        d0[3] = atan2f(acc0[3], acc0[2]) * INV2PI;
        d1[0] = sqrtf(acc1[0]*acc1[0] + acc1[1]*acc1[1]);
        d1[1] = atan2f(acc1[1], acc1[0]) * INV2PI;
        d1[2] = sqrtf(acc1[2]*acc1[2] + acc1[3]*acc1[3]);
        d1[3] = atan2f(acc1[3], acc1[2]) * INV2PI;
    }
}

// ---- fused QK (LDS-staged KtT) + amp-phase energy + softmax + colsum; 4 rows/block ----
__global__ __launch_bounds__(256) void k_energy3(
    const short* __restrict__ xqb, const short* __restrict__ KtT,
    const float* __restrict__ q1T, const float* __restrict__ angle_lrf,
    short* __restrict__ ETb, float* __restrict__ colsum)
{
    __shared__ short kt[512][68];          // padded: 136B row stride -> 2-way banks
    __shared__ float xqf[4][64];
    __shared__ float qs[4][64];
    __shared__ float divs[32];
    __shared__ float4 xw[4];
    const int b  = blockIdx.x >> 7;        // 4 x 128
    const int n0 = (blockIdx.x & 127) * 4;
    const int t = threadIdx.x;
    {
        const short* src = KtT + (size_t)b*512*64;
        #pragma unroll
        for (int i = 0; i < 16; ++i) {
            const int idx = t + 256*i;          // uint4 index, 4096 total
            const int row = idx >> 3, col = (idx & 7) * 8;
            const uint4 u = *(const uint4*)(src + (size_t)row*64 + col);
            *(uint2*)&kt[row][col]     = make_uint2(u.x, u.y);
            *(uint2*)&kt[row][col + 4] = make_uint2(u.z, u.w);
        }
    }
    if (t < 64) {
        #pragma unroll
        for (int i = 0; i < 4; ++i) {
            xqf[i][t] = bf2f(xqb[((size_t)b*512 + n0 + i)*64 + t]);
            qs[i][t]  = q1T[((size_t)b*512 + n0 + i)*64 + t];
        }
    } else if (t < 96) {
        divs[t-64] = __expf(-(float)(t-64) * DIVK);
    }
    __syncthreads();
    float acc[4][2];
    #pragma unroll
    for (int i = 0; i < 4; ++i) { acc[i][0] = 0.f; acc[i][1] = 0.f; }
    for (int c = 0; c < 64; c += 4) {
        float xv[4][4];
        #pragma unroll
        for (int i = 0; i < 4; ++i) {
            #pragma unroll
            for (int j = 0; j < 4; ++j) xv[i][j] = xqf[i][c + j];
        }
        #pragma unroll
        for (int mi = 0; mi < 2; ++mi) {
            const uint2 u = *(const uint2*)&kt[t + mi*256][c];
            const float k0 = bflo(u.x), k1 = bfhi(u.x);
            const float k2 = bflo(u.y), k3 = bfhi(u.y);
            #pragma unroll
            for (int i = 0; i < 4; ++i) {
                acc[i][mi] = fmaf(k0, xv[i][0],
                             fmaf(k1, xv[i][1],
                             fmaf(k2, xv[i][2],
                             fmaf(k3, xv[i][3], acc[i][mi]))));
            }
        }
    }
    float av[4][2];
    #pragma unroll
    for (int i = 0; i < 4; ++i) {
        av[i][0] = angle_lrf[((size_t)b*512 + n0 + i)*512 + t] * FCT_REV;
        av[i][1] = angle_lrf[((size_t)b*512 + n0 + i)*512 + t + 256] * FCT_REV;
    }
    #pragma unroll 2
    for (int j = 0; j < 32; ++j) {
        const float d = divs[j];
        #pragma unroll
        for (int i = 0; i < 4; ++i) {
            const float R = qs[i][2*j], ph = qs[i][2*j+1];
            #pragma unroll
            for (int m = 0; m < 2; ++m) {
                const float arg = fmaf(av[i][m], d, ph);
                acc[i][m] = fmaf(R, sinrev(arg), acc[i][m]);
            }
        }
    }
    float v0 = fmaxf(acc[0][0], acc[0][1]), v1 = fmaxf(acc[1][0], acc[1][1]);
    float v2 = fmaxf(acc[2][0], acc[2][1]), v3 = fmaxf(acc[3][0], acc[3][1]);
    #pragma unroll
    for (int off = 1; off < 64; off <<= 1) {
        v0 = fmaxf(v0, __shfl_xor(v0, off));
        v1 = fmaxf(v1, __shfl_xor(v1, off));
        v2 = fmaxf(v2, __shfl_xor(v2, off));
        v3 = fmaxf(v3, __shfl_xor(v3, off));
    }
    const int wid = t >> 6, lane = t & 63;
    if (lane == 0) { float4 f = {v0,v1,v2,v3}; xw[wid] = f; }
    __syncthreads();
    {
        const float4 a0 = xw[0], a1 = xw[1], a2 = xw[2], a3 = xw[3];
        v0 = fmaxf(fmaxf(a0.x,a1.x), fmaxf(a2.x,a3.x));
        v1 = fmaxf(fmaxf(a0.y,a1.y), fmaxf(a2.y,a3.y));
        v2 = fmaxf(fmaxf(a0.z,a1.z), fmaxf(a2.z,a3.z));
        v3 = fmaxf(fmaxf(a0.w,a1.w), fmaxf(a2.w,a3.w));
    }
    float p[4][2];
    p[0][0] = __expf(acc[0][0]-v0); p[0][1] = __expf(acc[0][1]-v0);
    p[1][0] = __expf(acc[1][0]-v1); p[1][1] = __expf(acc[1][1]-v1);
    p[2][0] = __expf(acc[2][0]-v2); p[2][1] = __expf(acc[2][1]-v2);
    p[3][0] = __expf(acc[3][0]-v3); p[3][1] = __expf(acc[3][1]-v3);
    float s0 = p[0][0]+p[0][1], s1 = p[1][0]+p[1][1];
    float s2 = p[2][0]+p[2][1], s3 = p[3][0]+p[3][1];
    #pragma unroll
    for (int off = 1; off < 64; off <<= 1) {
        s0 += __shfl_xor(s0, off); s1 += __shfl_xor(s1, off);
        s2 += __shfl_xor(s2, off); s3 += __shfl_xor(s3, off);
    }
    __syncthreads();
    if (lane == 0) { float4 f = {s0,s1,s2,s3}; xw[wid] = f; }
    __syncthreads();
    {
        const float4 a0 = xw[0], a1 = xw[1], a2 = xw[2], a3 = xw[3];
        s0 = (a0.x+a1.x) + (a2.x+a3.x);
        s1 = (a0.y+a1.y) + (a2.y+a3.y);
        s2 = (a0.z+a1.z) + (a2.z+a3.z);
        s3 = (a0.w+a1.w) + (a2.w+a3.w);
    }
    const float i0 = 1.f/s0, i1 = 1.f/s1, i2 = 1.f/s2, i3 = 1.f/s3;
    short* Eb = ETb + (size_t)b*512*512;
    #pragma unroll
    for (int mi = 0; mi < 2; ++mi) {
        const int m = t + mi*256;
        const float e0 = p[0][mi]*i0, e1 = p[1][mi]*i1, e2 = p[2][mi]*i2, e3 = p[3][mi]*i3;
        uint2 u;
        u.x = pk2(e0, e1);
        u.y = pk2(e2, e3);
        *(uint2*)(Eb + (size_t)m*512 + n0) = u;
        atomicAdd(&colsum[b*512 + m], (e0 + e1) + (e2 + e3));
    }
}

// ---- xr = 0.5*rc[m]*(vsum @ E) -> xrT bf16; also point_relation out ----
__global__ __launch_bounds__(256) void k_xr2(
    const short* __restrict__ vsumb, const short* __restrict__ ETb,
    const float* __restrict__ colsum, short* __restrict__ xrT,
    float* __restrict__ out)
{
    const int bid = blockIdx.x;            // 4 x 4 x 16 = 256
    const int b  = bid / 64;
    const int rt = (bid / 16) % 4;
    const int ct = bid % 16;
    const int r0 = rt*64, c0 = ct*32;
    const int w = threadIdx.x >> 6, lane = threadIdx.x & 63;
    const int lr = lane & 15, lg = lane >> 4;
    const short* ap  = vsumb + (size_t)b*256*512 + (size_t)(r0 + w*16 + lr)*512 + 8*lg;
    const short* bp0 = ETb + (size_t)b*512*512 + (size_t)(c0 + lr)*512 + 8*lg;
    const short* bp1 = bp0 + 16*512;
    f32x4 acc0 = {0.f,0.f,0.f,0.f}, acc1 = {0.f,0.f,0.f,0.f};
    #pragma unroll 4
    for (int kk = 0; kk < 512; kk += 32) {
        bf16x8 a  = *(const bf16x8*)(ap  + kk);
        bf16x8 b0 = *(const bf16x8*)(bp0 + kk);
        bf16x8 b1 = *(const bf16x8*)(bp1 + kk);
        acc0 = __builtin_amdgcn_mfma_f32_16x16x32_bf16(a, b0, acc0, 0, 0, 0);
        acc1 = __builtin_amdgcn_mfma_f32_16x16x32_bf16(a, b1, acc1, 0, 0, 0);
    }
    const int rowb = r0 + w*16 + lg*4;
    const int m0 = c0 + lr, m1 = m0 + 16;
    const float rc0 = 1.f / (1e-12f + colsum[b*512 + m0]);
    const float rc1 = 1.f / (1e-12f + colsum[b*512 + m1]);
    const float s0 = 0.5f * rc0, s1 = 0.5f * rc1;
    short* xb = xrT + (size_t)b*512*256;
    uint2 u;
    u.x = pk2(acc0[0]*s0, acc0[1]*s0);
    u.y = pk2(acc0[2]*s0, acc0[3]*s0);
    *(uint2*)(xb + (size_t)m0*256 + rowb) = u;
    u.x = pk2(acc1[0]*s1, acc1[1]*s1);
    u.y = pk2(acc1[2]*s1, acc1[3]*s1);
    *(uint2*)(xb + (size_t)m1*256 + rowb) = u;
    if (w == 0 && lg == 0) {   // point_relation (rt-duplicates write identical values)
        out[(size_t)4*256*512 + b*512 + m0] = bf2f(ETb[((size_t)b*512 + m0)*512]) * rc0;
        out[(size_t)4*256*512 + b*512 + m1] = bf2f(ETb[((size_t)b*512 + m1)*512]) * rc1;
    }
}

// ---- z = linx - linW @ xr + lin_b; fused BN partial stats (atomic) ----
__global__ __launch_bounds__(256) void k_z2st(
    const short* __restrict__ Wcatb, const short* __restrict__ xrT,
    const float* __restrict__ linx, const float* __restrict__ lin_b,
    float* __restrict__ z, float* __restrict__ stat)
{
    const int bid = blockIdx.x;            // 4 x 4 x 16 = 256
    const int b  = bid / 64;
    const int rt = (bid / 16) % 4;
    const int ct = bid % 16;
    const int r0 = rt*64, c0 = ct*32;
    const int w = threadIdx.x >> 6, lane = threadIdx.x & 63;
    const int lr = lane & 15, lg = lane >> 4;
    const short* ap  = Wcatb + (size_t)(384 + r0 + w*16 + lr)*512 + 8*lg;
    const short* bp0 = xrT + (size_t)b*512*256 + (size_t)(c0 + lr)*256 + 8*lg;
    const short* bp1 = bp0 + 16*256;
    f32x4 acc0 = {0.f,0.f,0.f,0.f}, acc1 = {0.f,0.f,0.f,0.f};
    #pragma unroll
    for (int kk = 0; kk < 256; kk += 32) {
        bf16x8 a  = *(const bf16x8*)(ap  + kk);
        bf16x8 b0 = *(const bf16x8*)(bp0 + kk);
        bf16x8 b1 = *(const bf16x8*)(bp1 + kk);
        acc0 = __builtin_amdgcn_mfma_f32_16x16x32_bf16(a, b0, acc0, 0, 0, 0);
        acc1 = __builtin_amdgcn_mfma_f32_16x16x32_bf16(a, b1, acc1, 0, 0, 0);
    }
    const int rowb = r0 + w*16 + lg*4;
    const int col0 = c0 + lr;
    const float* Lb = linx + (size_t)b*256*512;
    float* zb = z + (size_t)b*256*512;
    #pragma unroll
    for (int j = 0; j < 4; ++j) {
        const float lb = lin_b[rowb+j];
        const float z0 = Lb[(size_t)(rowb+j)*512 + col0]      - acc0[j] + lb;
        const float z1 = Lb[(size_t)(rowb+j)*512 + col0 + 16] - acc1[j] + lb;
        zb[(size_t)(rowb+j)*512 + col0]      = z0;
        zb[(size_t)(rowb+j)*512 + col0 + 16] = z1;
        float s  = z0 + z1;
        float s2 = z0*z0 + z1*z1;
        #pragma unroll
        for (int off = 1; off < 16; off <<= 1) {
            s  += __shfl_xor(s,  off);
            s2 += __shfl_xor(s2, off);
        }
        if (lr == 0) {
            atomicAdd(&stat[rowb+j], s);
            atomicAdd(&stat[256 + rowb+j], s2);
        }
    }
}

// ---- BN apply + exact gelu + residual (float4) ----
__global__ __launch_bounds__(256) void k_final(
    const float* __restrict__ x, const float* __restrict__ z,
    const float* __restrict__ stat, const float* __restrict__ gamma,
    const float* __restrict__ beta, float* __restrict__ out)
{
    const int gid = blockIdx.x*256 + threadIdx.x;   // 131072 x4 elems
    const int base = gid * 4;
    const int c = (base >> 9) & 255;
    const float mu  = stat[c] * (1.f/2048.f);
    const float var = stat[256 + c] * (1.f/2048.f) - mu*mu;
    const float gsc = gamma[c] * rsqrtf(var + 1e-5f);
    const float bt  = beta[c];
    const float4 zv = *(const float4*)&z[base];
    const float4 xv = *(const float4*)&x[base];
    float4 ov;
    {
        float y = (zv.x - mu)*gsc + bt;
        ov.x = xv.x + 0.5f*y*(1.f + erff(y*0.70710678118654752f));
        y = (zv.y - mu)*gsc + bt;
        ov.y = xv.y + 0.5f*y*(1.f + erff(y*0.70710678118654752f));
        y = (zv.z - mu)*gsc + bt;
        ov.z = xv.z + 0.5f*y*(1.f + erff(y*0.70710678118654752f));
        y = (zv.w - mu)*gsc + bt;
        ov.w = xv.w + 0.5f*y*(1.f + erff(y*0.70710678118654752f));
    }
    *(float4*)&out[base] = ov;
}

extern "C" void kernel_launch(void* const* d_in, const int* in_sizes, int n_in,
                              void* d_out, int out_size, void* d_ws, size_t ws_size,
                              hipStream_t stream)
{
    const float* x         = (const float*)d_in[0];
    const float* pca       = (const float*)d_in[1];
    const float* angle_lrf = (const float*)d_in[2];
    const float* angle_pca = (const float*)d_in[3];
    const float* Wkp       = (const float*)d_in[4];
    const float* Wk        = (const float*)d_in[5];
    const float* Wv        = (const float*)d_in[6];
    const float* Wvp       = (const float*)d_in[7];
    const float* e1W       = (const float*)d_in[8];
    const float* e2W       = (const float*)d_in[10];
    const float* linW      = (const float*)d_in[12];
    const float* linb      = (const float*)d_in[13];
    const float* gamma     = (const float*)d_in[14];
    const float* beta      = (const float*)d_in[15];

    char* w = (char*)d_ws;
    short* Wcatb  = (short*)(w + 0);          //   720896
    short* InTb   = (short*)(w + 720896);     //  2097152
    short* vsumb  = (short*)(w + 2818048);    //  1048576
    short* KtT    = (short*)(w + 3866624);    //   262144
    short* ETb    = (short*)(w + 4128768);    //  2097152
    short* xrT    = (short*)(w + 6225920);    //  1048576
    float* stat   = (float*)(w + 7274496);    //     2048
    float* colsum = (float*)(w + 7276544);    //     8192
    float* e2Wt   = (float*)(w + 7284736);    //    16384 (dead after k_gemm1)
    float* z      = (float*)(w + 7284736);    //  2097152 (written after e2Wt last read)
    short* xqb    = (short*)(w + 12003328);   //   262144
    float* q1T    = (float*)(w + 12265472);   //   524288
    float* linx   = (float*)(w + 12789760);   //  2097152 -> end 14886912
    float* out    = (float*)d_out;

    k_prep   <<<432, 256, 0, stream>>>(Wkp, Wk, Wv, Wvp, linW, e1W, e2W, x, pca,
                                       Wcatb, InTb, e2Wt, stat, colsum);
    k_gemm1  <<<704, 256, 0, stream>>>(Wcatb, InTb, angle_pca, e2Wt,
                                       xqb, KtT, vsumb, linx, q1T);
    k_energy3<<<512, 256, 0, stream>>>(xqb, KtT, q1T, angle_lrf, ETb, colsum);
    k_xr2    <<<256, 256, 0, stream>>>(vsumb, ETb, colsum, xrT, out);
    k_z2st   <<<256, 256, 0, stream>>>(Wcatb, xrT, linx, linb, z, stat);
    k_final  <<<512, 256, 0, stream>>>(x, z, stat, gamma, beta, out);
}